// Round 1
// baseline (1667.259 us; speedup 1.0000x reference)
//
#include <hip/hip_runtime.h>
#include <hip/hip_bf16.h>

// LSTM unroll, T=64 steps. Strategy:
//   prep:  Wt[n][k] = gate-interleaved transpose of [W;U] in bf16 (4 MB), biasr reordered.
//   step:  fused GEMM  z = [x_t | h] @ [W;U]  (M=1024, N=2048, K=1024, bf16 MFMA, fp32 acc)
//          + LSTM cell epilogue (sigmoid/tanh, c/h update) in one kernel, launched 64x.
// Gate interleave (n = 4*h + gate, gate order i,f,g,o) => epilogue reads all 4 gates of one
// h-unit as a single float4 from LDS.
// Tile: 64 rows x 64 z-cols per block -> grid 32x16 = 512 blocks = 2 blocks/CU.
// LDS rows padded 64->72 bf16 (+16B) => 2-way bank aliasing only (free on gfx950).

typedef __attribute__((ext_vector_type(8))) short bfrag8;   // 8 bf16 (4 VGPRs) MFMA A/B frag
typedef __attribute__((ext_vector_type(4))) float facc4;    // 4 fp32 MFMA C/D frag

#define T_STEPS 64

__device__ __forceinline__ unsigned short f2bf(float f) {
  unsigned int u = __float_as_uint(f);
  u += 0x7FFFu + ((u >> 16) & 1u);          // RNE
  return (unsigned short)(u >> 16);
}

__device__ __forceinline__ float sigm(float x) { return 1.0f / (1.0f + __expf(-x)); }
__device__ __forceinline__ float tanhf_(float x) { return 1.0f - 2.0f / (__expf(2.0f * x) + 1.0f); }

// Build Wt[2048][1024] bf16 (gate-interleaved, K-transposed) and biasr[2048] fp32.
//   Wt[4h+g][k] = (k<512 ? kernel[k][g*512+h] : recurrent[k-512][g*512+h])
__global__ void prep_kernel(const float* __restrict__ Wk, const float* __restrict__ Wr,
                            const float* __restrict__ bias,
                            unsigned short* __restrict__ Wt, float* __restrict__ biasr)
{
  int gid = (blockIdx.x << 8) + threadIdx.x;   // 0 .. 2M-1
  int k   = gid >> 11;                         // 0..1023
  int col = gid & 2047;                        // original column g*512+h
  float v = (k < 512) ? Wk[((size_t)k << 11) + col]
                      : Wr[((size_t)(k - 512) << 11) + col];
  int n = ((col & 511) << 2) | (col >> 9);     // 4*h + gate
  Wt[((size_t)n << 10) + k] = f2bf(v);
  if (gid < 2048) {
    biasr[((gid & 511) << 2) | (gid >> 9)] = bias[gid];
  }
}

// One LSTM step: per block computes z-tile (64 batch rows x 64 gate-interleaved cols
// = 16 h-units), then the cell update for those (row, h) pairs.
__global__ __launch_bounds__(256, 2)
void lstm_step(const float* __restrict__ x, const unsigned short* __restrict__ Wt,
               const float* __restrict__ biasr, unsigned short* __restrict__ Hbf,
               float* __restrict__ Cst, float* __restrict__ out, int t)
{
  __shared__ unsigned short As[64][72];   // A tile: rows = batch, cols = K chunk (padded)
  __shared__ unsigned short Bs[64][72];   // B tile: rows = n (z-col), cols = K chunk (B^T)
  __shared__ float Zs[64][68];            // z spill for epilogue (padded)

  const int tid  = threadIdx.x;
  const int lane = tid & 63;
  const int w    = tid >> 6;
  const int wm   = (w >> 1) & 1;          // wave row  (0..1) -> 32 rows
  const int wn   = w & 1;                 // wave col  (0..1) -> 32 cols
  const int llo  = lane & 15;
  const int lhi  = lane >> 4;

  const int m0 = blockIdx.y << 6;         // batch-row base (16 blocks * 64)
  const int n0 = blockIdx.x << 6;         // z-col base     (32 blocks * 64)
  const int h0 = blockIdx.x << 4;         // h base         (32 blocks * 16)

  facc4 acc00 = {0.f, 0.f, 0.f, 0.f};
  facc4 acc01 = acc00, acc10 = acc00, acc11 = acc00;

  const int sr = tid >> 2;                // staging row 0..63
  const int sc = (tid & 3) << 4;          // staging col {0,16,32,48}

  for (int ko = 0; ko < 16; ++ko) {
    const int kb = ko << 6;               // K base, 0..960
    uint4 a0, a1;
    if (kb < 512) {
      // A cols 0..511 come from x_t (fp32 -> bf16 on the fly)
      const float* src = x + (((size_t)(m0 + sr) << 6) + (size_t)t) * 512 + kb + sc;
      float4 v0 = *(const float4*)(src + 0);
      float4 v1 = *(const float4*)(src + 4);
      float4 v2 = *(const float4*)(src + 8);
      float4 v3 = *(const float4*)(src + 12);
      a0.x = f2bf(v0.x) | ((unsigned)f2bf(v0.y) << 16);
      a0.y = f2bf(v0.z) | ((unsigned)f2bf(v0.w) << 16);
      a0.z = f2bf(v1.x) | ((unsigned)f2bf(v1.y) << 16);
      a0.w = f2bf(v1.z) | ((unsigned)f2bf(v1.w) << 16);
      a1.x = f2bf(v2.x) | ((unsigned)f2bf(v2.y) << 16);
      a1.y = f2bf(v2.z) | ((unsigned)f2bf(v2.w) << 16);
      a1.z = f2bf(v3.x) | ((unsigned)f2bf(v3.y) << 16);
      a1.w = f2bf(v3.z) | ((unsigned)f2bf(v3.w) << 16);
    } else if (t > 0) {
      // A cols 512..1023 come from h_{t-1} (already bf16)
      const uint4* src = (const uint4*)(Hbf + ((size_t)(m0 + sr) << 9) + (kb - 512) + sc);
      a0 = src[0]; a1 = src[1];
    } else {
      a0 = make_uint4(0u, 0u, 0u, 0u); a1 = a0;   // h_{-1} = 0
    }
    const uint4* bsrc = (const uint4*)(Wt + ((size_t)(n0 + sr) << 10) + kb + sc);
    uint4 b0 = bsrc[0], b1 = bsrc[1];

    *(uint4*)&As[sr][sc]     = a0;
    *(uint4*)&As[sr][sc + 8] = a1;
    *(uint4*)&Bs[sr][sc]     = b0;
    *(uint4*)&Bs[sr][sc + 8] = b1;
    __syncthreads();

#pragma unroll
    for (int kk = 0; kk < 64; kk += 32) {
      // A frag: A[m=llo][k=lhi*8+j] ; B frag from B^T rows: B[k=lhi*8+j][n=llo]
      bfrag8 af0 = *(const bfrag8*)&As[(wm << 5) + llo][kk + (lhi << 3)];
      bfrag8 af1 = *(const bfrag8*)&As[(wm << 5) + 16 + llo][kk + (lhi << 3)];
      bfrag8 bf0 = *(const bfrag8*)&Bs[(wn << 5) + llo][kk + (lhi << 3)];
      bfrag8 bf1 = *(const bfrag8*)&Bs[(wn << 5) + 16 + llo][kk + (lhi << 3)];
      acc00 = __builtin_amdgcn_mfma_f32_16x16x32_bf16(af0, bf0, acc00, 0, 0, 0);
      acc01 = __builtin_amdgcn_mfma_f32_16x16x32_bf16(af0, bf1, acc01, 0, 0, 0);
      acc10 = __builtin_amdgcn_mfma_f32_16x16x32_bf16(af1, bf0, acc10, 0, 0, 0);
      acc11 = __builtin_amdgcn_mfma_f32_16x16x32_bf16(af1, bf1, acc11, 0, 0, 0);
    }
    __syncthreads();
  }

  // Spill accumulators: C/D layout col=lane&15, row=(lane>>4)*4+reg  [verified m89/m91]
#pragma unroll
  for (int rr = 0; rr < 4; ++rr) {
    int rbase = (wm << 5) + (lhi << 2) + rr;
    int cbase = (wn << 5) + llo;
    Zs[rbase][cbase]           = acc00[rr];
    Zs[rbase + 16][cbase]      = acc10[rr];
    Zs[rbase][cbase + 16]      = acc01[rr];
    Zs[rbase + 16][cbase + 16] = acc11[rr];
  }
  __syncthreads();

  // LSTM cell: each thread handles 4 (row, h) pairs; gates are contiguous float4.
  const int hs = tid & 15;
  const int rw = tid >> 4;
  const int h  = h0 + hs;
  float4 bb = *(const float4*)&biasr[(size_t)h << 2];
#pragma unroll
  for (int it = 0; it < 4; ++it) {
    int row = rw + (it << 4);
    int b   = m0 + row;
    float4 z = *(const float4*)&Zs[row][hs << 2];
    float ig = sigm(z.x + bb.x);
    float fg = sigm(z.y + bb.y);
    float gg = tanhf_(z.z + bb.z);
    float og = sigm(z.w + bb.w);
    size_t chIdx = ((size_t)b << 9) + h;
    float cp = (t == 0) ? 0.0f : Cst[chIdx];
    float cn = fg * cp + ig * gg;
    float hn = og * tanhf_(cn);
    Cst[chIdx] = cn;
    Hbf[chIdx] = f2bf(hn);
    out[((((size_t)b << 6) + (size_t)t) << 9) + h] = hn;
  }
}

extern "C" void kernel_launch(void* const* d_in, const int* in_sizes, int n_in,
                              void* d_out, int out_size, void* d_ws, size_t ws_size,
                              hipStream_t stream) {
  const float* x    = (const float*)d_in[0];   // [1024][64][512]
  const float* Wk   = (const float*)d_in[1];   // [512][2048]
  const float* Wr   = (const float*)d_in[2];   // [512][2048]
  const float* bias = (const float*)d_in[3];   // [2048]
  float* out = (float*)d_out;                  // [1024][64][512]

  char* ws = (char*)d_ws;
  // ws layout (all 16B-aligned): Wt 4MB | biasr 8KB | Hbf 1MB | Cst 2MB  (~7MB total)
  unsigned short* Wt    = (unsigned short*)(ws);
  float*          biasr = (float*)(ws + 4194304);
  unsigned short* Hbf   = (unsigned short*)(ws + 4202496);
  float*          Cst   = (float*)(ws + 5251072);

  prep_kernel<<<dim3(8192), dim3(256), 0, stream>>>(Wk, Wr, bias, Wt, biasr);
  for (int t = 0; t < T_STEPS; ++t) {
    lstm_step<<<dim3(32, 16), dim3(256), 0, stream>>>(x, Wt, biasr, Hbf, Cst, out, t);
  }
}